// Round 4
// baseline (449.367 us; speedup 1.0000x reference)
//
#include <hip/hip_runtime.h>
#include <cstdint>
#include <cstddef>

#define NIMG 256
#define PADW 18
#define XB_IMG (PADW * PADW * 256)   // 82944 elements per image
#define W2_ROW 2304                  // 9*256

typedef __bf16 bf16x8 __attribute__((ext_vector_type(8)));
typedef float floatx4 __attribute__((ext_vector_type(4)));
typedef float floatvec4 __attribute__((ext_vector_type(4)));

__device__ __forceinline__ unsigned short f2bf(float f) {
    unsigned u = __float_as_uint(f);
    u = (u + 0x7FFFu + ((u >> 16) & 1u)) >> 16;   // RNE
    return (unsigned short)u;
}

__device__ __forceinline__ void gload_lds16(const void* g, void* l) {
    __builtin_amdgcn_global_load_lds(
        (const __attribute__((address_space(1))) void*)g,
        (__attribute__((address_space(3))) void*)l, 16, 0, 0);
}

// ---------------------------------------------------------------------------
// Kernel 1 v2: x NCHW fp32 -> xb[n][py][px][c] bf16, padded 18x18, halo zeroed.
// float4 global reads, packed b64 LDS writes. (unchanged from R3)
// ---------------------------------------------------------------------------
__global__ __launch_bounds__(256) void convert_kernel(
        const float* __restrict__ x, unsigned short* __restrict__ xb) {
    __shared__ __align__(16) unsigned short tile2[64][268];
    const int n  = blockIdx.x;
    const int c0 = blockIdx.y * 64;
    const int t  = threadIdx.x;
    const float* xi = x + (size_t)n * 65536;
    unsigned short* xo = xb + (size_t)n * XB_IMG;

    if (blockIdx.y == 0) {
        #pragma unroll
        for (int it = 0; it < 17; ++it) {
            int idx = it * 256 + t;
            int hp = idx >> 6;
            int c4 = (idx & 63) * 4;
            int py, px;
            if (hp < 18)      { py = 0;       px = hp;      }
            else if (hp < 36) { py = 17;      px = hp - 18; }
            else if (hp < 52) { py = hp - 35; px = 0;       }
            else              { py = hp - 51; px = 17;      }
            *(uint2*)&xo[(py * 18 + px) * 256 + c4] = make_uint2(0u, 0u);
        }
    }

    {
        const int p4 = (t & 63) * 4;
        const int ci = t >> 6;
        #pragma unroll
        for (int i = 0; i < 16; ++i) {
            const int c = i * 4 + ci;
            floatvec4 v = *(const floatvec4*)&xi[(c0 + c) * 256 + p4];
            unsigned lo = (unsigned)f2bf(v.x) | ((unsigned)f2bf(v.y) << 16);
            unsigned hi = (unsigned)f2bf(v.z) | ((unsigned)f2bf(v.w) << 16);
            *(uint2*)&tile2[c][p4] = make_uint2(lo, hi);
        }
    }
    __syncthreads();

    #pragma unroll
    for (int it = 0; it < 32; ++it) {
        int idx = it * 256 + t;
        int p   = idx >> 5;
        int cp  = (idx & 31) * 2;
        unsigned lo = tile2[cp][p];
        unsigned hi = tile2[cp + 1][p];
        int py = (p >> 4) + 1, px = (p & 15) + 1;
        *(unsigned int*)&xo[(py * 18 + px) * 256 + c0 + cp] = lo | (hi << 16);
    }
}

// ---------------------------------------------------------------------------
// Kernel 2: combined circulant weight w2[kout][pos][c] bf16. (unchanged)
// ---------------------------------------------------------------------------
__global__ __launch_bounds__(256) void wprep_kernel(
        const float* __restrict__ wt, const float* __restrict__ alphas,
        unsigned short* __restrict__ w2) {
    __shared__ float wlds[16][257];
    const int o16 = blockIdx.x * 16;
    const int pos = blockIdx.y;
    const int t   = threadIdx.x;

    #pragma unroll
    for (int j = 0; j < 16; ++j)
        wlds[j][t] = wt[((o16 + j) * 256 + t) * 9 + pos];

    float a[5];
    {
        float mx = alphas[0];
        #pragma unroll
        for (int i = 1; i < 5; ++i) mx = fmaxf(mx, alphas[i]);
        float s = 0.f;
        #pragma unroll
        for (int i = 0; i < 5; ++i) { a[i] = __expf(alphas[i] - mx); s += a[i]; }
        float inv = 1.f / s;
        #pragma unroll
        for (int i = 0; i < 5; ++i) a[i] *= inv;
    }
    __syncthreads();

    const int c = t;
    #pragma unroll
    for (int oo = 0; oo < 16; ++oo) {
        float acc = a[0] * wlds[oo][c];
        #pragma unroll
        for (int bi = 0; bi < 4; ++bi) {
            const int b  = 2 << bi;            // 2,4,8,16
            const int r  = oo & (b - 1);
            const int cc = c & (b - 1);
            const int i0 = (r - cc) & (b - 1);
            const int ob = oo - r;
            const int icb = c - cc;
            float s2 = 0.f;
            for (int j = 0; j < b; ++j)
                s2 += wlds[ob + j][icb + ((j + i0) & (b - 1))];
            acc += a[1 + bi] * s2 * (1.f / (float)b);
        }
        w2[(size_t)(o16 + oo) * W2_ROW + pos * 256 + c] = f2bf(acc);
    }
}

// ---------------------------------------------------------------------------
// Kernel 3 v4: R2's proven 16x16x32 gemm (0 conflicts, verified swizzle)
// restructured as single-barrier ping-pong double-buffer:
//   per step: barrier -> issue step+1 loads into other buffer -> compute.
// Loads fly for one full compute phase before their vmcnt(0) drain at the
// next barrier => the m97 barrier-drain stall becomes a no-op. 36 barriers
// (vs 72). LDS 64 KB (2 buffers x (16+16) KB) -> 2 blocks/CU, accepted for
// true async overlap.
// ---------------------------------------------------------------------------
__global__ __launch_bounds__(256) void gemm_kernel(
        const unsigned short* __restrict__ xb,
        const unsigned short* __restrict__ w2,
        float* __restrict__ out) {
    __shared__ __align__(16) unsigned short xs[2][8192];  // [pixel][64ch]
    __shared__ __align__(16) unsigned short ws[2][8192];  // [kout ][64ch]

    const int t    = threadIdx.x;
    const int lane = t & 63;
    const int wid  = t >> 6;

    // XCD-paired decode: b&7 = XCD slot; both ktiles of a ptile share it.
    const int b     = blockIdx.x;
    const int s_    = b >> 3;                   // 0..127
    const int ptile = (b & 7) * 64 + (s_ >> 1); // 0..511
    const int ktile = s_ & 1;
    const int n_img = ptile >> 1;
    const int half  = ptile & 1;
    const int kbase = ktile * 128;

    // ---- staging: waves 0/1 -> xs, waves 2/3 -> ws; 8 rows per instr
    const int rlo  = lane >> 3;                        // row within 8-row chunk
    const int cswz = ((lane & 7) - rlo) & 7;           // swizzled ch-group
    const int coff = cswz * 8;

    int xg[8], wg[8];
    {
        const int sub = wid & 1;
        #pragma unroll
        for (int i = 0; i < 8; ++i) {
            int r = sub * 64 + i * 8 + rlo;            // tile row 0..127
            int y  = half * 8 + (r >> 4);
            int xq = r & 15;
            xg[i] = n_img * XB_IMG + ((y + 1) * 18 + (xq + 1)) * 256 + coff;
            int kr = kbase + sub * 64 + i * 8 + rlo;
            wg[i] = kr * W2_ROW + coff;
        }
    }
    const int lds_base = (wid & 1) * 4096;

    const floatx4 z4 = {0.f, 0.f, 0.f, 0.f};
    floatx4 acc[4][4];
    #pragma unroll
    for (int i = 0; i < 4; ++i)
        #pragma unroll
        for (int j = 0; j < 4; ++j) acc[i][j] = z4;

    // ---- reader offsets (swizzled) — identical pattern to R2 (0 conflicts)
    const int wrow = wid >> 1, wcol = wid & 1;
    const int arow = wrow * 64 + (lane & 15);
    const int brow = wcol * 64 + (lane & 15);
    const int sa0  = (arow + (lane >> 4)) & 7;
    const int sb0  = (brow + (lane >> 4)) & 7;

    // issue staging for step `st` into buffer `pp`
    auto issue = [&](int st, int pp) {
        const int pos = st >> 2;
        const int cs  = st & 3;
        if (wid < 2) {
            const int dy = pos / 3, dx = pos - dy * 3;
            const int go = (dy - 1) * (18 * 256) + (dx - 1) * 256 + cs * 64;
            #pragma unroll
            for (int i = 0; i < 8; ++i)
                gload_lds16(xb + xg[i] + go, &xs[pp][lds_base + i * 512]);
        } else {
            const int go = pos * 256 + cs * 64;
            #pragma unroll
            for (int i = 0; i < 8; ++i)
                gload_lds16(w2 + wg[i] + go, &ws[pp][lds_base + i * 512]);
        }
    };

    issue(0, 0);
    for (int step = 0; step < 36; ++step) {
        const int pp = step & 1;
        __syncthreads();                 // drains this step's loads (vmcnt0)
        if (step + 1 < 36) issue(step + 1, pp ^ 1);   // fly during compute

        #pragma unroll
        for (int ks = 0; ks < 2; ++ks) {
            const int sa = (sa0 + ks * 4) & 7;
            const int sb = (sb0 + ks * 4) & 7;
            bf16x8 af[4], bfr[4];
            #pragma unroll
            for (int mt = 0; mt < 4; ++mt)
                af[mt] = *(const bf16x8*)&ws[pp][(arow + mt * 16) * 64 + sa * 8];
            #pragma unroll
            for (int nt = 0; nt < 4; ++nt)
                bfr[nt] = *(const bf16x8*)&xs[pp][(brow + nt * 16) * 64 + sb * 8];
            #pragma unroll
            for (int mt = 0; mt < 4; ++mt)
                #pragma unroll
                for (int nt = 0; nt < 4; ++nt)
                    acc[mt][nt] = __builtin_amdgcn_mfma_f32_16x16x32_bf16(
                        af[mt], bfr[nt], acc[mt][nt], 0, 0, 0);
        }
    }

    // epilogue: C/D layout col=lane&15 (pixel, coalesced), row=(lane>>4)*4+r
    const int p0 = half * 128 + wcol * 64;
    const int k0 = kbase + wrow * 64;
    float* ob = out + (size_t)n_img * 65536;
    #pragma unroll
    for (int mt = 0; mt < 4; ++mt) {
        #pragma unroll
        for (int nt = 0; nt < 4; ++nt) {
            const int kout = k0 + mt * 16 + (lane >> 4) * 4;
            const int p    = p0 + nt * 16 + (lane & 15);
            #pragma unroll
            for (int r = 0; r < 4; ++r)
                ob[(kout + r) * 256 + p] = acc[mt][nt][r];
        }
    }
}

// ---------------------------------------------------------------------------
// Fallback (only if workspace too small for xb): naive conv using w2.
// ---------------------------------------------------------------------------
__global__ __launch_bounds__(256) void naive_conv(
        const float* __restrict__ x, const unsigned short* __restrict__ w2,
        float* __restrict__ out) {
    __shared__ float wr[2304];
    const int n = blockIdx.x >> 8, k = blockIdx.x & 255;
    const int t = threadIdx.x;
    for (int i = t; i < 2304; i += 256)
        wr[i] = __uint_as_float(((unsigned)w2[k * W2_ROW + i]) << 16);
    __syncthreads();
    const int y = t >> 4, xx = t & 15;
    const float* xi = x + (size_t)n * 65536;
    float acc = 0.f;
    for (int pos = 0; pos < 9; ++pos) {
        int dy = pos / 3 - 1, dx = pos % 3 - 1;
        int yy = y + dy, x2 = xx + dx;
        if (yy < 0 || yy > 15 || x2 < 0 || x2 > 15) continue;
        const float* xp = xi + yy * 16 + x2;
        const float* wp = wr + pos * 256;
        for (int c = 0; c < 256; ++c) acc += xp[c * 256] * wp[c];
    }
    out[(size_t)n * 65536 + k * 256 + t] = acc;
}

extern "C" void kernel_launch(void* const* d_in, const int* in_sizes, int n_in,
                              void* d_out, int out_size, void* d_ws, size_t ws_size,
                              hipStream_t stream) {
    const float* x      = (const float*)d_in[0];
    const float* wt     = (const float*)d_in[1];
    const float* alphas = (const float*)d_in[2];
    float* out = (float*)d_out;

    const size_t xb_elems = (size_t)NIMG * XB_IMG;          // 21,233,664
    const size_t w2_elems = (size_t)256 * W2_ROW;           //    589,824
    const size_t need = (xb_elems + w2_elems) * sizeof(unsigned short); // ~41.6 MB

    if (ws_size >= need) {
        unsigned short* xb = (unsigned short*)d_ws;
        unsigned short* w2 = xb + xb_elems;
        convert_kernel<<<dim3(256, 4), 256, 0, stream>>>(x, xb);
        wprep_kernel<<<dim3(16, 9), 256, 0, stream>>>(wt, alphas, w2);
        gemm_kernel<<<dim3(1024), 256, 0, stream>>>(xb, w2, out);
    } else if (ws_size >= w2_elems * sizeof(unsigned short)) {
        unsigned short* w2 = (unsigned short*)d_ws;
        wprep_kernel<<<dim3(16, 9), 256, 0, stream>>>(wt, alphas, w2);
        naive_conv<<<dim3(256 * 256), 256, 0, stream>>>(x, w2, out);
    }
}

// Round 5
// 203.212 us; speedup vs baseline: 2.2113x; 2.2113x over previous
//
#include <hip/hip_runtime.h>
#include <cstdint>
#include <cstddef>

#define NIMG 256
#define PADW 18
#define XB_IMG (PADW * PADW * 256)   // 82944 elements per image
#define W2_ROW 2304                  // 9*256

typedef __bf16 bf16x8 __attribute__((ext_vector_type(8)));
typedef float floatx4 __attribute__((ext_vector_type(4)));
typedef float floatvec4 __attribute__((ext_vector_type(4)));

__device__ __forceinline__ unsigned short f2bf(float f) {
    unsigned u = __float_as_uint(f);
    u = (u + 0x7FFFu + ((u >> 16) & 1u)) >> 16;   // RNE
    return (unsigned short)u;
}

__device__ __forceinline__ void gload_lds16(const void* g, void* l) {
    __builtin_amdgcn_global_load_lds(
        (const __attribute__((address_space(1))) void*)g,
        (__attribute__((address_space(3))) void*)l, 16, 0, 0);
}

// ---------------------------------------------------------------------------
// Kernel 1 v2: x NCHW fp32 -> xb[n][py][px][c] bf16, padded 18x18, halo zeroed.
// (unchanged)
// ---------------------------------------------------------------------------
__global__ __launch_bounds__(256) void convert_kernel(
        const float* __restrict__ x, unsigned short* __restrict__ xb) {
    __shared__ __align__(16) unsigned short tile2[64][268];
    const int n  = blockIdx.x;
    const int c0 = blockIdx.y * 64;
    const int t  = threadIdx.x;
    const float* xi = x + (size_t)n * 65536;
    unsigned short* xo = xb + (size_t)n * XB_IMG;

    if (blockIdx.y == 0) {
        #pragma unroll
        for (int it = 0; it < 17; ++it) {
            int idx = it * 256 + t;
            int hp = idx >> 6;
            int c4 = (idx & 63) * 4;
            int py, px;
            if (hp < 18)      { py = 0;       px = hp;      }
            else if (hp < 36) { py = 17;      px = hp - 18; }
            else if (hp < 52) { py = hp - 35; px = 0;       }
            else              { py = hp - 51; px = 17;      }
            *(uint2*)&xo[(py * 18 + px) * 256 + c4] = make_uint2(0u, 0u);
        }
    }

    {
        const int p4 = (t & 63) * 4;
        const int ci = t >> 6;
        #pragma unroll
        for (int i = 0; i < 16; ++i) {
            const int c = i * 4 + ci;
            floatvec4 v = *(const floatvec4*)&xi[(c0 + c) * 256 + p4];
            unsigned lo = (unsigned)f2bf(v.x) | ((unsigned)f2bf(v.y) << 16);
            unsigned hi = (unsigned)f2bf(v.z) | ((unsigned)f2bf(v.w) << 16);
            *(uint2*)&tile2[c][p4] = make_uint2(lo, hi);
        }
    }
    __syncthreads();

    #pragma unroll
    for (int it = 0; it < 32; ++it) {
        int idx = it * 256 + t;
        int p   = idx >> 5;
        int cp  = (idx & 31) * 2;
        unsigned lo = tile2[cp][p];
        unsigned hi = tile2[cp + 1][p];
        int py = (p >> 4) + 1, px = (p & 15) + 1;
        *(unsigned int*)&xo[(py * 18 + px) * 256 + c0 + cp] = lo | (hi << 16);
    }
}

// ---------------------------------------------------------------------------
// Kernel 2: combined circulant weight w2[kout][pos][c] bf16. (unchanged)
// ---------------------------------------------------------------------------
__global__ __launch_bounds__(256) void wprep_kernel(
        const float* __restrict__ wt, const float* __restrict__ alphas,
        unsigned short* __restrict__ w2) {
    __shared__ float wlds[16][257];
    const int o16 = blockIdx.x * 16;
    const int pos = blockIdx.y;
    const int t   = threadIdx.x;

    #pragma unroll
    for (int j = 0; j < 16; ++j)
        wlds[j][t] = wt[((o16 + j) * 256 + t) * 9 + pos];

    float a[5];
    {
        float mx = alphas[0];
        #pragma unroll
        for (int i = 1; i < 5; ++i) mx = fmaxf(mx, alphas[i]);
        float s = 0.f;
        #pragma unroll
        for (int i = 0; i < 5; ++i) { a[i] = __expf(alphas[i] - mx); s += a[i]; }
        float inv = 1.f / s;
        #pragma unroll
        for (int i = 0; i < 5; ++i) a[i] *= inv;
    }
    __syncthreads();

    const int c = t;
    #pragma unroll
    for (int oo = 0; oo < 16; ++oo) {
        float acc = a[0] * wlds[oo][c];
        #pragma unroll
        for (int bi = 0; bi < 4; ++bi) {
            const int b  = 2 << bi;            // 2,4,8,16
            const int r  = oo & (b - 1);
            const int cc = c & (b - 1);
            const int i0 = (r - cc) & (b - 1);
            const int ob = oo - r;
            const int icb = c - cc;
            float s2 = 0.f;
            for (int j = 0; j < b; ++j)
                s2 += wlds[ob + j][icb + ((j + i0) & (b - 1))];
            acc += a[1 + bi] * s2 * (1.f / (float)b);
        }
        w2[(size_t)(o16 + oo) * W2_ROW + pos * 256 + c] = f2bf(acc);
    }
}

// ---------------------------------------------------------------------------
// gemm helpers: issue one BK=64 staging step / compute one BK=64 step.
// Buffer pointers are COMPILE-TIME distinct __shared__ objects (xs0/xs1/
// ws0/ws1) so alias analysis can prove async LDS writes (next buffer) don't
// alias the ds_reads (current buffer) — the R4 runtime-index failure mode.
// ---------------------------------------------------------------------------
struct GemmCtx {
    const unsigned short* xb;
    const unsigned short* w2;
    int xg[8], wg[8];
    int wid, lds_base;
    int arow, brow, sa0, sb0;
};

__device__ __forceinline__ void issue_step(const GemmCtx& c, int st,
                                           unsigned short* XS,
                                           unsigned short* WS) {
    const int pos = st >> 2, cs = st & 3;
    if (c.wid < 2) {
        const int dy = pos / 3, dx = pos - dy * 3;
        const int go = (dy - 1) * (18 * 256) + (dx - 1) * 256 + cs * 64;
        #pragma unroll
        for (int i = 0; i < 8; ++i)
            gload_lds16(c.xb + c.xg[i] + go, &XS[c.lds_base + i * 512]);
    } else {
        const int go = pos * 256 + cs * 64;
        #pragma unroll
        for (int i = 0; i < 8; ++i)
            gload_lds16(c.w2 + c.wg[i] + go, &WS[c.lds_base + i * 512]);
    }
}

__device__ __forceinline__ void compute_step(const GemmCtx& c,
                                             const unsigned short* XS,
                                             const unsigned short* WS,
                                             floatx4 (&acc)[4][4]) {
    #pragma unroll
    for (int ks = 0; ks < 2; ++ks) {
        const int sa = (c.sa0 + ks * 4) & 7;
        const int sb = (c.sb0 + ks * 4) & 7;
        bf16x8 af[4], bfr[4];
        #pragma unroll
        for (int mt = 0; mt < 4; ++mt)
            af[mt] = *(const bf16x8*)&WS[(c.arow + mt * 16) * 64 + sa * 8];
        #pragma unroll
        for (int nt = 0; nt < 4; ++nt)
            bfr[nt] = *(const bf16x8*)&XS[(c.brow + nt * 16) * 64 + sb * 8];
        #pragma unroll
        for (int mt = 0; mt < 4; ++mt)
            #pragma unroll
            for (int nt = 0; nt < 4; ++nt)
                acc[mt][nt] = __builtin_amdgcn_mfma_f32_16x16x32_bf16(
                    af[mt], bfr[nt], acc[mt][nt], 0, 0, 0);
    }
}

// ---------------------------------------------------------------------------
// Kernel 3 v5: R2 gemm (16x16x32, 0-conflict swizzle) + single-barrier
// ping-pong across 4 distinct LDS buffers. Per step: barrier -> issue next
// step into other buffer -> compute current. Loads fly one full compute
// phase (~350cyc >= L2 latency) before the barrier vmcnt(0) drain.
// LDS 64 KB -> 2 blocks/CU (accepted for async overlap).
// ---------------------------------------------------------------------------
__global__ __launch_bounds__(256) void gemm_kernel(
        const unsigned short* __restrict__ xb,
        const unsigned short* __restrict__ w2,
        float* __restrict__ out) {
    __shared__ __align__(16) unsigned short xs0[8192];
    __shared__ __align__(16) unsigned short ws0[8192];
    __shared__ __align__(16) unsigned short xs1[8192];
    __shared__ __align__(16) unsigned short ws1[8192];

    const int t    = threadIdx.x;
    const int lane = t & 63;
    const int wid  = t >> 6;

    // XCD-paired decode: b&7 = XCD slot; both ktiles of a ptile share it.
    const int b     = blockIdx.x;
    const int s_    = b >> 3;                   // 0..127
    const int ptile = (b & 7) * 64 + (s_ >> 1); // 0..511
    const int ktile = s_ & 1;
    const int n_img = ptile >> 1;
    const int half  = ptile & 1;
    const int kbase = ktile * 128;

    GemmCtx c;
    c.xb = xb; c.w2 = w2; c.wid = wid;
    c.lds_base = (wid & 1) * 4096;

    // staging addresses: waves 0/1 -> xs, waves 2/3 -> ws; 8 rows per instr
    {
        const int rlo  = lane >> 3;
        const int cswz = ((lane & 7) - rlo) & 7;   // XOR swizzle in global addr
        const int coff = cswz * 8;
        const int sub  = wid & 1;
        #pragma unroll
        for (int i = 0; i < 8; ++i) {
            int r = sub * 64 + i * 8 + rlo;        // tile row 0..127
            int y  = half * 8 + (r >> 4);
            int xq = r & 15;
            c.xg[i] = n_img * XB_IMG + ((y + 1) * 18 + (xq + 1)) * 256 + coff;
            int kr = kbase + sub * 64 + i * 8 + rlo;
            c.wg[i] = kr * W2_ROW + coff;
        }
    }

    // reader offsets (swizzled) — identical pattern to R2 (proven 0 conflicts)
    const int wrow = wid >> 1, wcol = wid & 1;
    c.arow = wrow * 64 + (lane & 15);
    c.brow = wcol * 64 + (lane & 15);
    c.sa0  = (c.arow + (lane >> 4)) & 7;
    c.sb0  = (c.brow + (lane >> 4)) & 7;

    const floatx4 z4 = {0.f, 0.f, 0.f, 0.f};
    floatx4 acc[4][4];
    #pragma unroll
    for (int i = 0; i < 4; ++i)
        #pragma unroll
        for (int j = 0; j < 4; ++j) acc[i][j] = z4;

    issue_step(c, 0, xs0, ws0);
    for (int ds2 = 0; ds2 < 18; ++ds2) {
        const int st = ds2 * 2;
        __syncthreads();                       // drains loads for step st
        issue_step(c, st + 1, xs1, ws1);       // flies during compute
        compute_step(c, xs0, ws0, acc);

        __syncthreads();                       // drains loads for step st+1
        if (ds2 < 17) issue_step(c, st + 2, xs0, ws0);
        compute_step(c, xs1, ws1, acc);
    }

    // epilogue: C/D layout col=lane&15 (pixel, coalesced), row=(lane>>4)*4+r
    const int p0 = half * 128 + wcol * 64;
    const int k0 = kbase + wrow * 64;
    float* ob = out + (size_t)n_img * 65536;
    #pragma unroll
    for (int mt = 0; mt < 4; ++mt) {
        #pragma unroll
        for (int nt = 0; nt < 4; ++nt) {
            const int kout = k0 + mt * 16 + (lane >> 4) * 4;
            const int p    = p0 + nt * 16 + (lane & 15);
            #pragma unroll
            for (int r = 0; r < 4; ++r)
                ob[(kout + r) * 256 + p] = acc[mt][nt][r];
        }
    }
}

// ---------------------------------------------------------------------------
// Fallback (only if workspace too small for xb): naive conv using w2.
// ---------------------------------------------------------------------------
__global__ __launch_bounds__(256) void naive_conv(
        const float* __restrict__ x, const unsigned short* __restrict__ w2,
        float* __restrict__ out) {
    __shared__ float wr[2304];
    const int n = blockIdx.x >> 8, k = blockIdx.x & 255;
    const int t = threadIdx.x;
    for (int i = t; i < 2304; i += 256)
        wr[i] = __uint_as_float(((unsigned)w2[k * W2_ROW + i]) << 16);
    __syncthreads();
    const int y = t >> 4, xx = t & 15;
    const float* xi = x + (size_t)n * 65536;
    float acc = 0.f;
    for (int pos = 0; pos < 9; ++pos) {
        int dy = pos / 3 - 1, dx = pos % 3 - 1;
        int yy = y + dy, x2 = xx + dx;
        if (yy < 0 || yy > 15 || x2 < 0 || x2 > 15) continue;
        const float* xp = xi + yy * 16 + x2;
        const float* wp = wr + pos * 256;
        for (int c = 0; c < 256; ++c) acc += xp[c * 256] * wp[c];
    }
    out[(size_t)n * 65536 + k * 256 + t] = acc;
}

extern "C" void kernel_launch(void* const* d_in, const int* in_sizes, int n_in,
                              void* d_out, int out_size, void* d_ws, size_t ws_size,
                              hipStream_t stream) {
    const float* x      = (const float*)d_in[0];
    const float* wt     = (const float*)d_in[1];
    const float* alphas = (const float*)d_in[2];
    float* out = (float*)d_out;

    const size_t xb_elems = (size_t)NIMG * XB_IMG;          // 21,233,664
    const size_t w2_elems = (size_t)256 * W2_ROW;           //    589,824
    const size_t need = (xb_elems + w2_elems) * sizeof(unsigned short); // ~41.6 MB

    if (ws_size >= need) {
        unsigned short* xb = (unsigned short*)d_ws;
        unsigned short* w2 = xb + xb_elems;
        convert_kernel<<<dim3(256, 4), 256, 0, stream>>>(x, xb);
        wprep_kernel<<<dim3(16, 9), 256, 0, stream>>>(wt, alphas, w2);
        gemm_kernel<<<dim3(1024), 256, 0, stream>>>(xb, w2, out);
    } else if (ws_size >= w2_elems * sizeof(unsigned short)) {
        unsigned short* w2 = (unsigned short*)d_ws;
        wprep_kernel<<<dim3(16, 9), 256, 0, stream>>>(wt, alphas, w2);
        naive_conv<<<dim3(256 * 256), 256, 0, stream>>>(x, w2, out);
    }
}